// Round 1
// baseline (564.367 us; speedup 1.0000x reference)
//
#include <hip/hip_runtime.h>
#include <math.h>

#define NB 16
#define NN 1024
#define NH 32
#define NW 32
#define ND 256
#define NPIX (NB*NH*NW)        // 16384

// output layout (floats): z_q [16,256,32,32] | kl | indices [16,32,32] | perplexity
#define ZQ_OFF  0
#define KL_OFF  4194304
#define IDX_OFF 4194305
#define PPL_OFF 4210689

__device__ __forceinline__ float digamma_f(float x){
    // valid for x >= 1 (alpha = softplus+1 >= 1; S ~ 1700)
    float r = 0.f;
#pragma unroll
    for (int i = 0; i < 5; ++i){
        if (x < 6.f){ r -= 1.f/x; x += 1.f; }
    }
    float inv  = 1.f/x;
    float inv2 = inv*inv;
    return r + logf(x) - 0.5f*inv
             - inv2*(1.f/12.f - inv2*(1.f/120.f - inv2*(1.f/252.f)));
}

// ---------------------------------------------------------------------------
// Kernel 1: per-pixel stats + sample. One block per (b,h) row: 32 pixels.
// tid = w*8 + j ; thread (w,j) handles n = j, j+8, ... for pixel (b,h,w).
// Phase 1: alpha/S/lgamma/digamma sums, r = 2*(log(alpha)+gumbel) -> ws,
//          online softmax (m, Z) + argmax, 8-lane butterfly per pixel.
// Phase 2: sample = exp(r-m)/Z -> ws (overwrite), column sums -> colsum.
// ---------------------------------------------------------------------------
__global__ __launch_bounds__(256) void k_stats(
    const float* __restrict__ logits, const float* __restrict__ noise,
    float* __restrict__ smp, float* __restrict__ colsum,
    float* __restrict__ klsum, float* __restrict__ out)
{
    __shared__ float cs[NN];
    __shared__ float klbuf[NW];
    const int tid = threadIdx.x;
    const int bh  = blockIdx.x;
    const int b = bh >> 5, h = bh & 31;
    const int j = tid & 7, w = tid >> 3;
    const int p = (b*NH + h)*NW + w;

    for (int n = tid; n < NN; n += 256) cs[n] = 0.f;

    const float* lg_base = logits + (size_t)b*NN*NH*NW + (size_t)h*NW + w;
    const float* nz_base = noise  + (size_t)p*NN;
    float*       r_base  = smp    + (size_t)p*NN;

    float S = 0.f, L = 0.f, P = 0.f;
    float m = -INFINITY, Z = 0.f;
    int   idx = 0;

    for (int n = j; n < NN; n += 8){
        float x  = lg_base[(size_t)n*(NH*NW)];
        float sp = fmaxf(x, 0.f) + log1pf(expf(-fabsf(x)));   // softplus
        float a  = sp + 1.f;
        S += a;
        L += lgammaf(a);
        P += (a - 1.f)*digamma_f(a);
        float u = nz_base[n];
        float g = -logf(-logf(u));                 // gumbel
        float r = 2.f*(logf(a) + g);               // (log p + g)/TEMP up to const shift
        r_base[n] = r;
        if (r > m){ Z = Z*expf(m - r) + 1.f; m = r; idx = n; }
        else      { Z += expf(r - m); }
    }

    // butterfly over the 8 j-lanes of this pixel (lanes are consecutive tids)
#pragma unroll
    for (int mask = 1; mask < 8; mask <<= 1){
        float So = __shfl_xor(S, mask);
        float Lo = __shfl_xor(L, mask);
        float Po = __shfl_xor(P, mask);
        float mo = __shfl_xor(m, mask);
        float Zo = __shfl_xor(Z, mask);
        int   io = __shfl_xor(idx, mask);
        S += So; L += Lo; P += Po;
        float mn = fmaxf(m, mo);
        Z = Z*expf(m - mn) + Zo*expf(mo - mn);
        idx = (mo > m || (mo == m && io < idx)) ? io : idx;
        m = mn;
    }

    if (j == 0){
        out[IDX_OFF + p] = (float)idx;
        float kl = lgammaf(S) - L - lgammaf(1024.f)
                 + (P - digamma_f(S)*(S - 1024.f));
        klbuf[w] = kl;
    }
    __syncthreads();     // also drains vmcnt -> r_base stores visible below
    if (tid == 0){
        float s = 0.f;
        for (int i = 0; i < NW; ++i) s += klbuf[i];
        atomicAdd(klsum, s);
    }

    // phase 2: sample + column sums
    const float invZ = 1.f/Z;
    for (int n = j; n < NN; n += 8){
        float r = r_base[n];
        float s = expf(r - m)*invZ;
        r_base[n] = s;
        float t = s;                       // sum over the 8 w's in this wave
        t += __shfl_xor(t, 8);
        t += __shfl_xor(t, 16);
        t += __shfl_xor(t, 32);
        if ((tid & 56) == 0) atomicAdd(&cs[n], t);
    }
    __syncthreads();
    for (int n = tid; n < NN; n += 256) atomicAdd(&colsum[n], cs[n]);
}

// ---------------------------------------------------------------------------
// Kernel 2: z_q GEMM (fp32).  C[p,d] = sum_k smp[p,k]*cb[k,d]
// Block tile 64 pixels x 128 d, BK=32, 256 threads, micro-tile 8d x 4q.
// Output [B,D,H,W]: float4 stores along q (contiguous).
// ---------------------------------------------------------------------------
#define BM 64
#define BN 128
#define BK 32

__global__ __launch_bounds__(256) void k_gemm(
    const float* __restrict__ smp, const float* __restrict__ cb,
    float* __restrict__ out)
{
    __shared__ float As[BK][BM + 4];   // stride 68 floats = 272 B (16B aligned)
    __shared__ float Bs[BK][BN + 8];   // stride 136 floats = 544 B (16B aligned)
    const int tid = threadIdx.x;
    const int tx = tid & 15;           // q group: 4*tx
    const int ty = tid >> 4;           // d group: 8*ty
    const int p0 = blockIdx.x * BM;
    const int d0 = blockIdx.y * BN;

    float acc[8][4];
#pragma unroll
    for (int i = 0; i < 8; ++i)
#pragma unroll
        for (int q = 0; q < 4; ++q) acc[i][q] = 0.f;

    for (int k0 = 0; k0 < NN; k0 += BK){
#pragma unroll
        for (int t = 0; t < 2; ++t){           // A: 64x32 -> LDS transposed
            int id  = tid + t*256;
            int row = id >> 3, c4 = id & 7;
            float4 v = *(const float4*)&smp[(size_t)(p0+row)*NN + k0 + c4*4];
            As[c4*4+0][row] = v.x;
            As[c4*4+1][row] = v.y;
            As[c4*4+2][row] = v.z;
            As[c4*4+3][row] = v.w;
        }
#pragma unroll
        for (int t = 0; t < 4; ++t){           // B: 32x128
            int id = tid + t*256;
            int kr = id >> 5, c4 = id & 31;
            *(float4*)&Bs[kr][c4*4] =
                *(const float4*)&cb[(size_t)(k0+kr)*ND + d0 + c4*4];
        }
        __syncthreads();
#pragma unroll
        for (int k = 0; k < BK; ++k){
            float4 a  = *(const float4*)&As[k][4*tx];
            float4 b0 = *(const float4*)&Bs[k][8*ty];
            float4 b1 = *(const float4*)&Bs[k][8*ty+4];
            float av[4] = {a.x, a.y, a.z, a.w};
            float bv[8] = {b0.x, b0.y, b0.z, b0.w, b1.x, b1.y, b1.z, b1.w};
#pragma unroll
            for (int i = 0; i < 8; ++i)
#pragma unroll
                for (int q = 0; q < 4; ++q)
                    acc[i][q] = fmaf(bv[i], av[q], acc[i][q]);
        }
        __syncthreads();
    }

    const int bb = p0 >> 10;                       // batch (tile within one b)
    const int q0 = (p0 & 1023) + 4*tx;             // h*32+w base
#pragma unroll
    for (int i = 0; i < 8; ++i){
        int d = d0 + 8*ty + i;
        float4 v = make_float4(acc[i][0], acc[i][1], acc[i][2], acc[i][3]);
        *(float4*)&out[(size_t)bb*(ND*1024) + (size_t)d*1024 + q0] = v;
    }
}

// ---------------------------------------------------------------------------
// Kernel 3: finalize kl_loss + perplexity
// ---------------------------------------------------------------------------
__global__ __launch_bounds__(256) void k_final(
    const float* __restrict__ colsum, const float* __restrict__ klsum,
    float* __restrict__ out)
{
    __shared__ float red[4];
    const int tid = threadIdx.x;
    float s = 0.f;
    for (int n = tid; n < NN; n += 256){
        float avg = colsum[n] * (1.f/16384.f);
        s += avg * logf(avg + 1e-10f);
    }
#pragma unroll
    for (int mask = 1; mask < 64; mask <<= 1) s += __shfl_xor(s, mask);
    if ((tid & 63) == 0) red[tid >> 6] = s;
    __syncthreads();
    if (tid == 0){
        float tot = red[0] + red[1] + red[2] + red[3];
        out[PPL_OFF] = expf(-tot);
        out[KL_OFF]  = 1e-3f * (klsum[0] * (1.f/16384.f));
    }
}

extern "C" void kernel_launch(void* const* d_in, const int* in_sizes, int n_in,
                              void* d_out, int out_size, void* d_ws, size_t ws_size,
                              hipStream_t stream)
{
    const float* logits = (const float*)d_in[0];
    const float* cb     = (const float*)d_in[1];
    const float* noise  = (const float*)d_in[2];
    float* out = (float*)d_out;

    float* smp    = (float*)d_ws;                      // 16384*1024 fp32 = 64 MB
    float* colsum = smp + (size_t)NPIX*NN;             // 1024 fp32
    float* klsum  = colsum + NN;                       // 1 fp32

    hipMemsetAsync(colsum, 0, (NN + 1)*sizeof(float), stream);
    k_stats<<<dim3(NB*NH), 256, 0, stream>>>(logits, noise, smp, colsum, klsum, out);
    k_gemm <<<dim3(NPIX/BM, ND/BN), 256, 0, stream>>>(smp, cb, out);
    k_final<<<1, 256, 0, stream>>>(colsum, klsum, out);
}

// Round 2
// 379.960 us; speedup vs baseline: 1.4853x; 1.4853x over previous
//
#include <hip/hip_runtime.h>
#include <math.h>

#define NB 16
#define NN 1024
#define NH 32
#define NW 32
#define ND 256
#define NPIX (NB*NH*NW)        // 16384

// output layout (floats): z_q [16,256,32,32] | kl | indices [16,32,32] | perplexity
#define ZQ_OFF  0
#define KL_OFF  4194304
#define IDX_OFF 4194305
#define PPL_OFF 4210689

#define LGAMMA_1024F 6071.2804f
#define EXP_NEG16 1.1253517e-7f

__device__ __forceinline__ float fast_rcp(float x){ return __builtin_amdgcn_rcpf(x); }

// lgamma+digamma for a in [1, ~8]: shift by 4, Stirling at z=a+4 (z>=5).
// Shares log(z), log(prod), and two rcp between the two results.
__device__ __forceinline__ void lgamma_digamma(float a, float& lg, float& dg){
    float a1 = a + 1.f, a2 = a + 2.f, a3 = a + 3.f, z = a + 4.f;
    float p01 = a*a1, p23 = a2*a3;
    float prod = p01*p23;
    float rz = fast_rcp(z);
    float rp = fast_rcp(prod);
    float lz = __logf(z);
    float lp = __logf(prod);
    float rz2 = rz*rz;
    lg = (z - 0.5f)*lz - z + 0.918938533f
       + rz*(0.083333333f - 0.002777778f*rz2) - lp;
    float sr = ((a + a + 1.f)*p23 + (a + a + 5.f)*p01)*rp;
    dg = lz - 0.5f*rz - rz2*(0.083333333f - 0.008333333f*rz2) - sr;
}

// ---------------------------------------------------------------------------
// k_stats: single pass. Block = 16 pixels of one (b,h) row (full 64B logits
// line per n). 16 lanes per pixel, lane j handles n = j + 16k, k<64.
// Per element: a = softplus+1; Stirling lgamma/digamma; e = (a/ln u)^2 e^-16
// (== exp(2(log a + gumbel)) up to a constant; softmax-shift-invariant).
// Wave-level butterfly (masks 1,2,4,8) for S,L,P,Z and (max,argmax).
// Outputs: smp = unnormalized e (fp32), zinv[p] = 1/Z, indices, kl atomic.
// ---------------------------------------------------------------------------
__global__ __launch_bounds__(256) void k_stats(
    const float* __restrict__ logits, const float* __restrict__ noise,
    float* __restrict__ smp, float* __restrict__ zinv,
    float* __restrict__ klsum, float* __restrict__ out)
{
    __shared__ float klbuf[16];
    const int tid  = threadIdx.x;
    const int row  = blockIdx.x >> 1;         // b*32 + h
    const int w0   = (blockIdx.x & 1) * 16;
    const int b    = row >> 5, h = row & 31;
    const int j    = tid & 15;                // lane-in-pixel
    const int wl   = (tid >> 4) & 15;         // pixel-in-block  (v*4 + q)
    const int w    = w0 + wl;
    const int p    = row*32 + w;

    const float* lg_p = logits + (size_t)b*(NN*NH*NW) + (size_t)j*(NH*NW) + h*NW + w;
    const float* nz_p = noise  + (size_t)p*NN + j;
    float*       e_p  = smp    + (size_t)p*NN + j;

    float S = 0.f, L = 0.f, P = 0.f, Z = 0.f;
    float mx = -1.f;
    int   idx = 0;
    int   n = j;

#pragma unroll 8
    for (int k = 0; k < 64; ++k){
        float x = lg_p[0];
        float u = nz_p[0];
        // softplus + 1
        float t  = __expf(-fabsf(x));
        float a  = fmaxf(x, 0.f) + __logf(1.f + t) + 1.f;
        // lgamma / digamma
        float lga, dga;
        lgamma_digamma(a, lga, dga);
        S += a; L += lga; P += (a - 1.f)*dga;
        // ln(u): precise near u->1 (HW v_log has ~2^-22 abs error there)
        float d = 1.f - u;
        float lup = -d*(1.f + d*(0.5f + d*(0.33333333f + d*(0.25f
                  + d*(0.2f + d*(0.16666667f + d*0.14285714f))))));
        float lu = (d < 0.09f) ? lup : __logf(u);
        float ar = a * fast_rcp(lu);
        float e  = ar*ar*EXP_NEG16;           // ∝ exp((log α + gumbel)/TEMP)
        Z += e;
        e_p[0] = e;
        bool take = (e > mx);
        mx  = take ? e : mx;
        idx = take ? n : idx;
        n += 16;
        lg_p += 16*(NH*NW);
        nz_p += 16;
        e_p  += 16;
    }

    // butterfly over the 16 j-lanes of this pixel (consecutive lanes)
#pragma unroll
    for (int mask = 1; mask < 16; mask <<= 1){
        S += __shfl_xor(S, mask);
        L += __shfl_xor(L, mask);
        P += __shfl_xor(P, mask);
        Z += __shfl_xor(Z, mask);
        float mo = __shfl_xor(mx, mask);
        int   io = __shfl_xor(idx, mask);
        bool take = (mo > mx) || (mo == mx && io < idx);
        mx  = take ? mo : mx;
        idx = take ? io : idx;
    }

    if (j == 0){
        out[IDX_OFF + p] = (float)idx;
        zinv[p] = fast_rcp(Z);
        float rS = fast_rcp(S);
        float lnS = __logf(S);
        float lgS = (S - 0.5f)*lnS - S + 0.918938533f + 0.083333333f*rS;
        float dgS = lnS - 0.5f*rS;
        klbuf[wl] = lgS - L - LGAMMA_1024F + (P - dgS*(S - 1024.f));
    }
    __syncthreads();
    if (tid == 0){
        float s = 0.f;
#pragma unroll
        for (int i = 0; i < 16; ++i) s += klbuf[i];
        atomicAdd(klsum, s);
    }
}

// ---------------------------------------------------------------------------
// k_colsum: colsum[n] = sum_p e[p][n] * zinv[p].  Block = 32 pixels,
// thread t owns n-quad 4t..4t+3 (float4 loads, fully coalesced).
// ---------------------------------------------------------------------------
__global__ __launch_bounds__(256) void k_colsum(
    const float* __restrict__ smp, const float* __restrict__ zinv,
    float* __restrict__ colsum)
{
    const int t  = threadIdx.x;
    const int p0 = blockIdx.x * 32;
    float ax = 0.f, ay = 0.f, az = 0.f, aw = 0.f;
#pragma unroll 4
    for (int p = 0; p < 32; ++p){
        float zi = zinv[p0 + p];
        float4 v = *(const float4*)&smp[(size_t)(p0 + p)*NN + 4*t];
        ax += v.x*zi; ay += v.y*zi; az += v.z*zi; aw += v.w*zi;
    }
    atomicAdd(&colsum[4*t + 0], ax);
    atomicAdd(&colsum[4*t + 1], ay);
    atomicAdd(&colsum[4*t + 2], az);
    atomicAdd(&colsum[4*t + 3], aw);
}

// ---------------------------------------------------------------------------
// k_gemm: z_q[p,d] = zinv[p] * sum_k e[p,k]*cb[k,d]   (fp32, 64x128 tile)
// Row-scale by zinv is folded into A-staging.
// ---------------------------------------------------------------------------
#define BM 64
#define BN 128
#define BK 32

__global__ __launch_bounds__(256) void k_gemm(
    const float* __restrict__ smp, const float* __restrict__ cb,
    const float* __restrict__ zinv, float* __restrict__ out)
{
    __shared__ float As[BK][BM + 4];
    __shared__ float Bs[BK][BN + 8];
    const int tid = threadIdx.x;
    const int tx = tid & 15;
    const int ty = tid >> 4;
    const int p0 = blockIdx.x * BM;
    const int d0 = blockIdx.y * BN;

    const int r0 = tid >> 3, c40 = tid & 7;
    const float zi0 = zinv[p0 + r0];
    const float zi1 = zinv[p0 + r0 + 32];

    float acc[8][4];
#pragma unroll
    for (int i = 0; i < 8; ++i)
#pragma unroll
        for (int q = 0; q < 4; ++q) acc[i][q] = 0.f;

    for (int k0 = 0; k0 < NN; k0 += BK){
#pragma unroll
        for (int t = 0; t < 2; ++t){
            int row = r0 + t*32;
            float zi = t ? zi1 : zi0;
            float4 v = *(const float4*)&smp[(size_t)(p0+row)*NN + k0 + c40*4];
            As[c40*4+0][row] = v.x*zi;
            As[c40*4+1][row] = v.y*zi;
            As[c40*4+2][row] = v.z*zi;
            As[c40*4+3][row] = v.w*zi;
        }
#pragma unroll
        for (int t = 0; t < 4; ++t){
            int id = tid + t*256;
            int kr = id >> 5, c4 = id & 31;
            *(float4*)&Bs[kr][c4*4] =
                *(const float4*)&cb[(size_t)(k0+kr)*ND + d0 + c4*4];
        }
        __syncthreads();
#pragma unroll
        for (int k = 0; k < BK; ++k){
            float4 a  = *(const float4*)&As[k][4*tx];
            float4 b0 = *(const float4*)&Bs[k][8*ty];
            float4 b1 = *(const float4*)&Bs[k][8*ty+4];
            float av[4] = {a.x, a.y, a.z, a.w};
            float bv[8] = {b0.x, b0.y, b0.z, b0.w, b1.x, b1.y, b1.z, b1.w};
#pragma unroll
            for (int i = 0; i < 8; ++i)
#pragma unroll
                for (int q = 0; q < 4; ++q)
                    acc[i][q] = fmaf(bv[i], av[q], acc[i][q]);
        }
        __syncthreads();
    }

    const int bb = p0 >> 10;
    const int q0 = (p0 & 1023) + 4*tx;
#pragma unroll
    for (int i = 0; i < 8; ++i){
        int d = d0 + 8*ty + i;
        float4 v = make_float4(acc[i][0], acc[i][1], acc[i][2], acc[i][3]);
        *(float4*)&out[(size_t)bb*(ND*1024) + (size_t)d*1024 + q0] = v;
    }
}

// ---------------------------------------------------------------------------
// k_final: kl_loss + perplexity
// ---------------------------------------------------------------------------
__global__ __launch_bounds__(256) void k_final(
    const float* __restrict__ colsum, const float* __restrict__ klsum,
    float* __restrict__ out)
{
    __shared__ float red[4];
    const int tid = threadIdx.x;
    float s = 0.f;
    for (int n = tid; n < NN; n += 256){
        float avg = colsum[n] * (1.f/16384.f);
        s += avg * logf(avg + 1e-10f);
    }
#pragma unroll
    for (int mask = 1; mask < 64; mask <<= 1) s += __shfl_xor(s, mask);
    if ((tid & 63) == 0) red[tid >> 6] = s;
    __syncthreads();
    if (tid == 0){
        float tot = red[0] + red[1] + red[2] + red[3];
        out[PPL_OFF] = expf(-tot);
        out[KL_OFF]  = 1e-3f * (klsum[0] * (1.f/16384.f));
    }
}

extern "C" void kernel_launch(void* const* d_in, const int* in_sizes, int n_in,
                              void* d_out, int out_size, void* d_ws, size_t ws_size,
                              hipStream_t stream)
{
    const float* logits = (const float*)d_in[0];
    const float* cb     = (const float*)d_in[1];
    const float* noise  = (const float*)d_in[2];
    float* out = (float*)d_out;

    float* smp    = (float*)d_ws;                      // 16M fp32 = 64 MB
    float* zinv   = smp + (size_t)NPIX*NN;             // 16384
    float* colsum = zinv + NPIX;                       // 1024
    float* klsum  = colsum + NN;                       // 1

    hipMemsetAsync(colsum, 0, (NN + 1)*sizeof(float), stream);
    k_stats <<<dim3(NB*NH*2), 256, 0, stream>>>(logits, noise, smp, zinv, klsum, out);
    k_colsum<<<dim3(NPIX/32), 256, 0, stream>>>(smp, zinv, colsum);
    k_gemm  <<<dim3(NPIX/BM, ND/BN), 256, 0, stream>>>(smp, cb, zinv, out);
    k_final <<<1, 256, 0, stream>>>(colsum, klsum, out);
}

// Round 3
// 272.329 us; speedup vs baseline: 2.0724x; 1.3952x over previous
//
#include <hip/hip_runtime.h>
#include <math.h>

#define NB 16
#define NN 1024
#define NH 32
#define NW 32
#define ND 256
#define NPIX (NB*NH*NW)        // 16384

// output layout (floats): z_q [16,256,32,32] | kl | indices [16,32,32] | perplexity
#define ZQ_OFF  0
#define KL_OFF  4194304
#define IDX_OFF 4194305
#define PPL_OFF 4210689

#define LGAMMA_1024F 6071.2804f
#define EXP_NEG16 1.1253517e-7f

typedef _Float16 f16x8 __attribute__((ext_vector_type(8)));
typedef _Float16 f16x4 __attribute__((ext_vector_type(4)));
typedef float    f32x4 __attribute__((ext_vector_type(4)));

__device__ __forceinline__ float fast_rcp(float x){ return __builtin_amdgcn_rcpf(x); }

// lgamma+digamma for a in [1, ~8]: shift by 4, Stirling at z=a+4 (z>=5).
__device__ __forceinline__ void lgamma_digamma(float a, float& lg, float& dg){
    float a1 = a + 1.f, a2 = a + 2.f, a3 = a + 3.f, z = a + 4.f;
    float p01 = a*a1, p23 = a2*a3;
    float prod = p01*p23;
    float rz = fast_rcp(z);
    float rp = fast_rcp(prod);
    float lz = __logf(z);
    float lp = __logf(prod);
    float rz2 = rz*rz;
    lg = (z - 0.5f)*lz - z + 0.918938533f
       + rz*(0.083333333f - 0.002777778f*rz2) - lp;
    float sr = ((a + a + 1.f)*p23 + (a + a + 5.f)*p01)*rp;
    dg = lz - 0.5f*rz - rz2*(0.083333333f - 0.008333333f*rz2) - sr;
}

// ---------------------------------------------------------------------------
// k_stats (unchanged from R2): e = (a/ln u)^2 * e^-16 to smp (fp32), zinv,
// indices, kl atomic.
// ---------------------------------------------------------------------------
__global__ __launch_bounds__(256) void k_stats(
    const float* __restrict__ logits, const float* __restrict__ noise,
    float* __restrict__ smp, float* __restrict__ zinv,
    float* __restrict__ klsum, float* __restrict__ out)
{
    __shared__ float klbuf[16];
    const int tid  = threadIdx.x;
    const int row  = blockIdx.x >> 1;         // b*32 + h
    const int w0   = (blockIdx.x & 1) * 16;
    const int b    = row >> 5, h = row & 31;
    const int j    = tid & 15;                // lane-in-pixel
    const int wl   = (tid >> 4) & 15;         // pixel-in-block
    const int w    = w0 + wl;
    const int p    = row*32 + w;

    const float* lg_p = logits + (size_t)b*(NN*NH*NW) + (size_t)j*(NH*NW) + h*NW + w;
    const float* nz_p = noise  + (size_t)p*NN + j;
    float*       e_p  = smp    + (size_t)p*NN + j;

    float S = 0.f, L = 0.f, P = 0.f, Z = 0.f;
    float mx = -1.f;
    int   idx = 0;
    int   n = j;

#pragma unroll 8
    for (int k = 0; k < 64; ++k){
        float x = lg_p[0];
        float u = nz_p[0];
        float t  = __expf(-fabsf(x));
        float a  = fmaxf(x, 0.f) + __logf(1.f + t) + 1.f;
        float lga, dga;
        lgamma_digamma(a, lga, dga);
        S += a; L += lga; P += (a - 1.f)*dga;
        float d = 1.f - u;
        float lup = -d*(1.f + d*(0.5f + d*(0.33333333f + d*(0.25f
                  + d*(0.2f + d*(0.16666667f + d*0.14285714f))))));
        float lu = (d < 0.09f) ? lup : __logf(u);
        float ar = a * fast_rcp(lu);
        float e  = ar*ar*EXP_NEG16;
        Z += e;
        e_p[0] = e;
        bool take = (e > mx);
        mx  = take ? e : mx;
        idx = take ? n : idx;
        n += 16;
        lg_p += 16*(NH*NW);
        nz_p += 16;
        e_p  += 16;
    }

#pragma unroll
    for (int mask = 1; mask < 16; mask <<= 1){
        S += __shfl_xor(S, mask);
        L += __shfl_xor(L, mask);
        P += __shfl_xor(P, mask);
        Z += __shfl_xor(Z, mask);
        float mo = __shfl_xor(mx, mask);
        int   io = __shfl_xor(idx, mask);
        bool take = (mo > mx) || (mo == mx && io < idx);
        mx  = take ? mo : mx;
        idx = take ? io : idx;
    }

    if (j == 0){
        out[IDX_OFF + p] = (float)idx;
        zinv[p] = fast_rcp(Z);
        float rS = fast_rcp(S);
        float lnS = __logf(S);
        float lgS = (S - 0.5f)*lnS - S + 0.918938533f + 0.083333333f*rS;
        float dgS = lnS - 0.5f*rS;
        klbuf[wl] = lgS - L - LGAMMA_1024F + (P - dgS*(S - 1024.f));
    }
    __syncthreads();
    if (tid == 0){
        float s = 0.f;
#pragma unroll
        for (int i = 0; i < 16; ++i) s += klbuf[i];
        atomicAdd(klsum, s);
    }
}

// ---------------------------------------------------------------------------
// k_tr: transpose codebook [1024k][256d] f32 -> cbT[kb][d][32k] f16
// (32 k-blocks). Makes gemm A-fragments direct, coalesced global loads.
// ---------------------------------------------------------------------------
__global__ __launch_bounds__(256) void k_tr(
    const float* __restrict__ cb, _Float16* __restrict__ cbT)
{
    __shared__ float T[32][260];
    const int t  = threadIdx.x;
    const int kb = blockIdx.x;
#pragma unroll
    for (int i = 0; i < 8; ++i){
        int u = t + 256*i;
        int k = u >> 6, d4 = (u & 63)*4;
        float4 v = *(const float4*)&cb[(size_t)(kb*32 + k)*ND + d4];
        T[k][d4+0] = v.x; T[k][d4+1] = v.y; T[k][d4+2] = v.z; T[k][d4+3] = v.w;
    }
    __syncthreads();
    _Float16 hv[32];
#pragma unroll
    for (int k = 0; k < 32; ++k) hv[k] = (_Float16)T[k][t];
    _Float16* dst = cbT + (size_t)kb*8192 + (size_t)t*32;
#pragma unroll
    for (int j2 = 0; j2 < 4; ++j2)
        *(f16x8*)(dst + 8*j2) = *(f16x8*)&hv[8*j2];
}

// ---------------------------------------------------------------------------
// k_colsum: colsum[n] = sum_p e[p][n]*zinv[p]. 256 blocks x 64 pixels,
// register accumulation, 4 atomics/thread (256 adds per address total).
// ---------------------------------------------------------------------------
__global__ __launch_bounds__(256) void k_colsum(
    const float* __restrict__ smp, const float* __restrict__ zinv,
    float* __restrict__ colsum)
{
    const int t  = threadIdx.x;
    const int P0 = blockIdx.x * 64;
    float a0 = 0.f, a1 = 0.f, a2 = 0.f, a3 = 0.f;
#pragma unroll 4
    for (int p = 0; p < 64; ++p){
        float zi = zinv[P0 + p];
        float4 v = *(const float4*)&smp[(size_t)(P0 + p)*NN + 4*t];
        a0 += v.x*zi; a1 += v.y*zi; a2 += v.z*zi; a3 += v.w*zi;
    }
    atomicAdd(&colsum[4*t + 0], a0);
    atomicAdd(&colsum[4*t + 1], a1);
    atomicAdd(&colsum[4*t + 2], a2);
    atomicAdd(&colsum[4*t + 3], a3);
}

// ---------------------------------------------------------------------------
// k_gemm: z_q^T tiles via mfma_f32_16x16x32_f16.  D[m=d][n=p] = cbT(d,k)*s(k,p)
// Block: 64 pixels x all 256 d, 4 waves (wave v owns d 64v..64v+63).
// A-frags: direct global from cbT (perfectly coalesced, L2-resident).
// B: smp f32 -> *zinv -> f16 -> LDS (double-buffered, stride 56).
// ---------------------------------------------------------------------------
__global__ __launch_bounds__(256) void k_gemm(
    const float* __restrict__ smp, const _Float16* __restrict__ cbT,
    const float* __restrict__ zinv, float* __restrict__ out)
{
    __shared__ _Float16 Bs[2][64][56];
    const int t    = threadIdx.x;
    const int lane = t & 63;
    const int wv   = t >> 6;            // wave id -> d base 64*wv
    const int p0   = blockIdx.x * 64;

    // B staging map: thread -> (p = t>>3 and +32, k-quad = t&7)
    const int sp  = t >> 3, skq = t & 7;
    const float zi0 = zinv[p0 + sp];
    const float zi1 = zinv[p0 + sp + 32];
    const float* b0p = smp + (size_t)(p0 + sp)*NN + skq*4;
    const float* b1p = smp + (size_t)(p0 + sp + 32)*NN + skq*4;

    // fragment maps
    const int fn = lane & 15;           // n (pixel within 16-tile) / m (d within)
    const int fq = lane >> 4;           // quad
    const _Float16* aBase = cbT + (size_t)(64*wv + fn)*32 + fq*8;

    f32x4 acc[4][4];
#pragma unroll
    for (int mt = 0; mt < 4; ++mt)
#pragma unroll
        for (int nt = 0; nt < 4; ++nt) acc[mt][nt] = (f32x4)0.f;

    // stage kb=0
    {
        float4 v0 = *(const float4*)b0p;
        float4 v1 = *(const float4*)b1p;
        f16x4 h0, h1;
        h0[0]=(_Float16)(v0.x*zi0); h0[1]=(_Float16)(v0.y*zi0);
        h0[2]=(_Float16)(v0.z*zi0); h0[3]=(_Float16)(v0.w*zi0);
        h1[0]=(_Float16)(v1.x*zi1); h1[1]=(_Float16)(v1.y*zi1);
        h1[2]=(_Float16)(v1.z*zi1); h1[3]=(_Float16)(v1.w*zi1);
        *(f16x4*)&Bs[0][sp][skq*4]      = h0;
        *(f16x4*)&Bs[0][sp + 32][skq*4] = h1;
    }
    f16x8 aCur[4];
#pragma unroll
    for (int mt = 0; mt < 4; ++mt)
        aCur[mt] = *(const f16x8*)(aBase + mt*512);
    __syncthreads();

    for (int kb = 0; kb < 32; ++kb){
        const int buf = kb & 1;
        const bool more = (kb + 1) < 32;
        float4 nv0, nv1;
        f16x8 aN[4];
        if (more){
            nv0 = *(const float4*)(b0p + (kb+1)*32);
            nv1 = *(const float4*)(b1p + (kb+1)*32);
#pragma unroll
            for (int mt = 0; mt < 4; ++mt)
                aN[mt] = *(const f16x8*)(aBase + (size_t)(kb+1)*8192 + mt*512);
        }
        f16x8 bf[4];
#pragma unroll
        for (int nt = 0; nt < 4; ++nt)
            bf[nt] = *(const f16x8*)&Bs[buf][nt*16 + fn][fq*8];
#pragma unroll
        for (int mt = 0; mt < 4; ++mt)
#pragma unroll
            for (int nt = 0; nt < 4; ++nt)
                acc[mt][nt] = __builtin_amdgcn_mfma_f32_16x16x32_f16(
                    aCur[mt], bf[nt], acc[mt][nt], 0, 0, 0);
        if (more){
            const int nbuf = 1 - buf;
            f16x4 h0, h1;
            h0[0]=(_Float16)(nv0.x*zi0); h0[1]=(_Float16)(nv0.y*zi0);
            h0[2]=(_Float16)(nv0.z*zi0); h0[3]=(_Float16)(nv0.w*zi0);
            h1[0]=(_Float16)(nv1.x*zi1); h1[1]=(_Float16)(nv1.y*zi1);
            h1[2]=(_Float16)(nv1.z*zi1); h1[3]=(_Float16)(nv1.w*zi1);
            *(f16x4*)&Bs[nbuf][sp][skq*4]      = h0;
            *(f16x4*)&Bs[nbuf][sp + 32][skq*4] = h1;
#pragma unroll
            for (int mt = 0; mt < 4; ++mt) aCur[mt] = aN[mt];
        }
        __syncthreads();
    }

    const int bb = p0 >> 10;
    const int q0 = p0 & 1023;
    float* outp = out + (size_t)bb*(ND*1024) + q0;
#pragma unroll
    for (int mt = 0; mt < 4; ++mt){
#pragma unroll
        for (int nt = 0; nt < 4; ++nt){
            const int pl = nt*16 + fn;
#pragma unroll
            for (int r = 0; r < 4; ++r){
                const int d = 64*wv + 16*mt + fq*4 + r;
                outp[(size_t)d*1024 + pl] = acc[mt][nt][r];
            }
        }
    }
}

// ---------------------------------------------------------------------------
// k_final: kl_loss + perplexity
// ---------------------------------------------------------------------------
__global__ __launch_bounds__(256) void k_final(
    const float* __restrict__ colsum, const float* __restrict__ klsum,
    float* __restrict__ out)
{
    __shared__ float red[4];
    const int tid = threadIdx.x;
    float s = 0.f;
    for (int n = tid; n < NN; n += 256){
        float avg = colsum[n] * (1.f/16384.f);
        s += avg * logf(avg + 1e-10f);
    }
#pragma unroll
    for (int mask = 1; mask < 64; mask <<= 1) s += __shfl_xor(s, mask);
    if ((tid & 63) == 0) red[tid >> 6] = s;
    __syncthreads();
    if (tid == 0){
        float tot = red[0] + red[1] + red[2] + red[3];
        out[PPL_OFF] = expf(-tot);
        out[KL_OFF]  = 1e-3f * (klsum[0] * (1.f/16384.f));
    }
}

extern "C" void kernel_launch(void* const* d_in, const int* in_sizes, int n_in,
                              void* d_out, int out_size, void* d_ws, size_t ws_size,
                              hipStream_t stream)
{
    const float* logits = (const float*)d_in[0];
    const float* cb     = (const float*)d_in[1];
    const float* noise  = (const float*)d_in[2];
    float* out = (float*)d_out;

    float* smp    = (float*)d_ws;                      // 16M fp32 = 64 MB
    float* zinv   = smp + (size_t)NPIX*NN;             // 16384
    float* colsum = zinv + NPIX;                       // 1024
    float* klsum  = colsum + NN;                       // 1
    size_t off    = ((size_t)NPIX*NN + NPIX + NN + 1 + 7) & ~(size_t)7;
    _Float16* cbT = (_Float16*)((float*)d_ws + off);   // 256K f16 = 512 KB

    hipMemsetAsync(colsum, 0, (NN + 1)*sizeof(float), stream);
    k_tr    <<<dim3(32),       256, 0, stream>>>(cb, cbT);
    k_stats <<<dim3(NB*NH*2),  256, 0, stream>>>(logits, noise, smp, zinv, klsum, out);
    k_colsum<<<dim3(NPIX/64),  256, 0, stream>>>(smp, zinv, colsum);
    k_gemm  <<<dim3(NPIX/64),  256, 0, stream>>>(smp, cbT, zinv, out);
    k_final <<<1, 256, 0, stream>>>(colsum, klsum, out);
}

// Round 4
// 271.927 us; speedup vs baseline: 2.0754x; 1.0015x over previous
//
#include <hip/hip_runtime.h>
#include <math.h>

#define NB 16
#define NN 1024
#define NH 32
#define NW 32
#define ND 256
#define NPIX (NB*NH*NW)        // 16384

// output layout (floats): z_q [16,256,32,32] | kl | indices [16,32,32] | perplexity
#define ZQ_OFF  0
#define KL_OFF  4194304
#define IDX_OFF 4194305
#define PPL_OFF 4210689

#define LGAMMA_1024F 6071.2804f
// e^-16 / 256  (2^-8 exact scale keeps argmax order; prevents f16 overflow)
#define EXP_C 4.3959832e-10f

// Bs: 16 rows (pixels) x 1024 f16, row stride 1040 f16 = 2080 B (16B-mult).
// Chunk = 16B = 8 f16. Chunk index c in [0,128); stored at c ^ (row & 7).
#define BS_ROW_B 2080

typedef _Float16 f16x8 __attribute__((ext_vector_type(8)));
typedef _Float16 f16x2 __attribute__((ext_vector_type(2)));
typedef float    f32x4 __attribute__((ext_vector_type(4)));

__device__ __forceinline__ float fast_rcp(float x){ return __builtin_amdgcn_rcpf(x); }

// lgamma+digamma for a in [1, ~8]: shift by 4, Stirling at z=a+4 (z>=5).
__device__ __forceinline__ void lgamma_digamma(float a, float& lg, float& dg){
    float a1 = a + 1.f, a2 = a + 2.f, a3 = a + 3.f, z = a + 4.f;
    float p01 = a*a1, p23 = a2*a3;
    float prod = p01*p23;
    float rz = fast_rcp(z);
    float rp = fast_rcp(prod);
    float lz = __logf(z);
    float lp = __logf(prod);
    float rz2 = rz*rz;
    lg = (z - 0.5f)*lz - z + 0.918938533f
       + rz*(0.083333333f - 0.002777778f*rz2) - lp;
    float sr = ((a + a + 1.f)*p23 + (a + a + 5.f)*p01)*rp;
    dg = lz - 0.5f*rz - rz2*(0.083333333f - 0.008333333f*rz2) - sr;
}

// one element: alpha, stats accumulation, e' = (a/ln u)^2 * e^-16 * 2^-8
__device__ __forceinline__ float elem(float x, float u,
                                      float& S, float& L, float& P){
    float t  = __expf(-fabsf(x));
    float a  = fmaxf(x, 0.f) + __logf(1.f + t) + 1.f;
    float lg, dg;
    lgamma_digamma(a, lg, dg);
    S += a; L += lg; P += (a - 1.f)*dg;
    float d = 1.f - u;
    float lup = -d*(1.f + d*(0.5f + d*(0.33333333f + d*(0.25f
              + d*(0.2f + d*(0.16666667f + d*0.14285714f))))));
    float lu = (d < 0.09f) ? lup : __logf(u);
    float ar = a * fast_rcp(lu);
    return ar*ar*EXP_C;
}

// ---------------------------------------------------------------------------
// k_tr: cb [1024n][256d] f32 -> cbT2[kb][d][32kk] f16 with the k-permutation
// n(K) = ((K>>1)&15) + 32*(K>>5) + 16*(K&1), K = kb*32 + kk.
// ---------------------------------------------------------------------------
__global__ __launch_bounds__(256) void k_tr(
    const float* __restrict__ cb, _Float16* __restrict__ cbT2)
{
    const int kb = blockIdx.x, d = threadIdx.x;
    _Float16 tmp[32];
#pragma unroll
    for (int kk = 0; kk < 32; ++kk){
        int n = 32*kb + ((kk >> 1) & 15) + 16*(kk & 1);
        tmp[kk] = (_Float16)cb[(size_t)n*ND + d];
    }
    _Float16* dst = cbT2 + (size_t)kb*8192 + (size_t)d*32;
#pragma unroll
    for (int i = 0; i < 4; ++i) *(f16x8*)(dst + 8*i) = *(f16x8*)&tmp[8*i];
}

// ---------------------------------------------------------------------------
// k_mega: stats + sample(LDS f16) + colsum partials + MFMA GEMM, one barrier.
// Block = 16 pixels of one (b,h) row-half. lane j (of 16) x pixel wl (of 16).
// ---------------------------------------------------------------------------
__global__ __launch_bounds__(256, 4) void k_mega(
    const float* __restrict__ logits, const float* __restrict__ noise,
    const _Float16* __restrict__ cbT2, float* __restrict__ colpart,
    float* __restrict__ klsum, float* __restrict__ out)
{
    __shared__ __align__(16) char lds[16*BS_ROW_B + 128];
    char*  bsb   = lds;
    float* zibuf = (float*)(lds + 16*BS_ROW_B);
    float* klbuf = zibuf + 16;

    const int t   = threadIdx.x;
    const int row = blockIdx.x >> 1;          // b*32 + h
    const int w0  = (blockIdx.x & 1) * 16;
    const int b   = row >> 5, h = row & 31;
    const int j   = t & 15;                   // lane-in-pixel
    const int wl  = t >> 4;                   // pixel-in-block
    const int p   = row*32 + w0 + wl;

    const float* lg_p = logits + (size_t)b*(NN*NH*NW) + (size_t)j*(NH*NW)
                      + (size_t)h*NW + w0 + wl;
    const float* nz_p = noise  + (size_t)p*NN + j;

    const int wrow = wl*BS_ROW_B;
    const int swz  = wl & 7;
    const int jsub = 4*(j & 3);
    const int jc   = j >> 2;

    float S = 0.f, L = 0.f, P = 0.f, Z = 0.f;
    float mx = -1.f;
    int   idx = 0;

#pragma unroll 4
    for (int k2 = 0; k2 < 32; ++k2){
        float x0 = lg_p[0];
        float u0 = nz_p[0];
        float x1 = lg_p[16*NH*NW];
        float u1 = nz_p[16];
        float e0 = elem(x0, u0, S, L, P);
        float e1 = elem(x1, u1, S, L, P);
        Z += e0 + e1;
        if (e0 > mx){ mx = e0; idx = j + 32*k2; }
        if (e1 > mx){ mx = e1; idx = j + 32*k2 + 16; }
        f16x2 hp; hp[0] = (_Float16)e0; hp[1] = (_Float16)e1;
        *(f16x2*)(bsb + wrow + ((((k2 << 2) | jc) ^ swz) << 4) + jsub) = hp;
        lg_p += 32*NH*NW;
        nz_p += 32;
    }

    // butterfly over the 16 j-lanes of this pixel
#pragma unroll
    for (int mask = 1; mask < 16; mask <<= 1){
        S += __shfl_xor(S, mask);
        L += __shfl_xor(L, mask);
        P += __shfl_xor(P, mask);
        Z += __shfl_xor(Z, mask);
        float mo = __shfl_xor(mx, mask);
        int   io = __shfl_xor(idx, mask);
        bool take = (mo > mx) || (mo == mx && io < idx);
        mx  = take ? mo : mx;
        idx = take ? io : idx;
    }

    const float zinv = fast_rcp(Z);
    if (j == 0){
        out[IDX_OFF + p] = (float)idx;
        zibuf[wl] = zinv;
        float rS = fast_rcp(S);
        float lnS = __logf(S);
        float lgS = (S - 0.5f)*lnS - S + 0.918938533f + 0.083333333f*rS;
        float dgS = lnS - 0.5f*rS;
        klbuf[wl] = lgS - L - LGAMMA_1024F + (P - dgS*(S - 1024.f));
    }

    // colsum partials: re-read own pairs, scale, reduce over wave's 4 pixels
    const int wv = t >> 6;
    float* crow = colpart + (size_t)(blockIdx.x*4 + wv)*NN + j;
#pragma unroll
    for (int c = 0; c < 4; ++c){
        float v[16];
#pragma unroll
        for (int i = 0; i < 8; ++i){
            int k2 = 8*c + i;
            f16x2 hp = *(f16x2*)(bsb + wrow + ((((k2 << 2) | jc) ^ swz) << 4) + jsub);
            v[2*i]   = (float)hp[0] * zinv;
            v[2*i+1] = (float)hp[1] * zinv;
        }
#pragma unroll
        for (int i = 0; i < 16; ++i){
            v[i] += __shfl_xor(v[i], 16);
            v[i] += __shfl_xor(v[i], 32);
        }
        if ((t & 48) == 0){
#pragma unroll
            for (int i = 0; i < 8; ++i){
                int k2 = 8*c + i;
                crow[32*k2]      = v[2*i];
                crow[32*k2 + 16] = v[2*i+1];
            }
        }
    }

    __syncthreads();     // Bs + zibuf + klbuf visible to all
    if (t == 0){
        float s = 0.f;
#pragma unroll
        for (int i = 0; i < 16; ++i) s += klbuf[i];
        atomicAdd(klsum, s);
    }

    // ---- GEMM: D[d][p] += cbT2(d,K) * Bs(p,K), K-permuted space ----
    const int lane = t & 63;
    const int fn = lane & 15;         // pixel col / d row within tile
    const int fq = lane >> 4;
    const _Float16* aBase = cbT2 + (size_t)(64*wv + fn)*32 + fq*8;
    const char* bRow = bsb + fn*BS_ROW_B;
    const int fswz = fn & 7;

    f32x4 acc[4];
#pragma unroll
    for (int mt = 0; mt < 4; ++mt) acc[mt] = (f32x4)0.f;

    f16x8 aCur[4];
#pragma unroll
    for (int mt = 0; mt < 4; ++mt) aCur[mt] = *(const f16x8*)(aBase + mt*512);

    for (int kb = 0; kb < 32; ++kb){
        const bool more = (kb + 1) < 32;
        f16x8 aN[4];
        if (more){
#pragma unroll
            for (int mt = 0; mt < 4; ++mt)
                aN[mt] = *(const f16x8*)(aBase + (size_t)(kb+1)*8192 + mt*512);
        }
        f16x8 bf = *(const f16x8*)(bRow + ((((kb << 2) | fq) ^ fswz) << 4));
#pragma unroll
        for (int mt = 0; mt < 4; ++mt)
            acc[mt] = __builtin_amdgcn_mfma_f32_16x16x32_f16(aCur[mt], bf, acc[mt], 0, 0, 0);
        if (more){
#pragma unroll
            for (int mt = 0; mt < 4; ++mt) aCur[mt] = aN[mt];
        }
    }

    const float zi = zibuf[fn];
    float* outp = out + (size_t)b*(ND*1024) + h*32 + w0;
#pragma unroll
    for (int mt = 0; mt < 4; ++mt){
#pragma unroll
        for (int r = 0; r < 4; ++r){
            int d = 64*wv + 16*mt + 4*fq + r;
            outp[(size_t)d*1024 + fn] = acc[mt][r]*zi;
        }
    }
}

// ---------------------------------------------------------------------------
// k_red: colsum[n] = sum over 4096 colpart rows. 64 blocks: 16 row-slices x
// 4 n-slices; 16 atomics per colsum address.
// ---------------------------------------------------------------------------
__global__ __launch_bounds__(256) void k_red(
    const float* __restrict__ colpart, float* __restrict__ colsum)
{
    const int n  = (blockIdx.x & 3)*256 + threadIdx.x;
    const int r0 = (blockIdx.x >> 2)*256;
    float s = 0.f;
#pragma unroll 8
    for (int r = 0; r < 256; ++r)
        s += colpart[(size_t)(r0 + r)*NN + n];
    atomicAdd(&colsum[n], s);
}

// ---------------------------------------------------------------------------
// k_final: kl_loss + perplexity
// ---------------------------------------------------------------------------
__global__ __launch_bounds__(256) void k_final(
    const float* __restrict__ colsum, const float* __restrict__ klsum,
    float* __restrict__ out)
{
    __shared__ float red[4];
    const int tid = threadIdx.x;
    float s = 0.f;
    for (int n = tid; n < NN; n += 256){
        float avg = colsum[n] * (1.f/16384.f);
        s += avg * logf(avg + 1e-10f);
    }
#pragma unroll
    for (int mask = 1; mask < 64; mask <<= 1) s += __shfl_xor(s, mask);
    if ((tid & 63) == 0) red[tid >> 6] = s;
    __syncthreads();
    if (tid == 0){
        float tot = red[0] + red[1] + red[2] + red[3];
        out[PPL_OFF] = expf(-tot);
        out[KL_OFF]  = 1e-3f * (klsum[0] * (1.f/16384.f));
    }
}

extern "C" void kernel_launch(void* const* d_in, const int* in_sizes, int n_in,
                              void* d_out, int out_size, void* d_ws, size_t ws_size,
                              hipStream_t stream)
{
    const float* logits = (const float*)d_in[0];
    const float* cb     = (const float*)d_in[1];
    const float* noise  = (const float*)d_in[2];
    float* out = (float*)d_out;

    float* colpart = (float*)d_ws;                       // 4096*1024 f32 = 16 MB
    float* colsum  = colpart + (size_t)4096*NN;          // 1024
    float* klsum   = colsum + NN;                        // 1
    _Float16* cbT2 = (_Float16*)(colsum + NN + 4);       // 512 KB (16B-aligned)

    hipMemsetAsync(colsum, 0, (NN + 1)*sizeof(float), stream);
    k_tr   <<<dim3(32),   256, 0, stream>>>(cb, cbT2);
    k_mega <<<dim3(1024), 256, 0, stream>>>(logits, noise, cbT2, colpart, klsum, out);
    k_red  <<<dim3(64),   256, 0, stream>>>(colpart, colsum);
    k_final<<<1, 256, 0, stream>>>(colsum, klsum, out);
}